// Round 4
// baseline (677.373 us; speedup 1.0000x reference)
//
#include <hip/hip_runtime.h>
#include <math.h>

namespace {
constexpr int LSEQ = 32;
constexpr int CDIM = 64;
constexpr int HDIM = 128;
constexpr int FDIM = 32;
constexpr float TWO_PI = 6.28318530717958647692f;

__device__ __forceinline__ float sigf(float x) { return 1.0f / (1.0f + __expf(-x)); }
__device__ __forceinline__ float tanh_fast(float x) { return 1.0f - 2.0f / (__expf(2.0f * x) + 1.0f); }
}

// S=4 sequences/block, 256 blocks (1/CU), 1024 threads (16 waves -> 4 waves/SIMD).
__global__ __launch_bounds__(1024, 4)
void sfm_lstm_s4w16(const float* __restrict__ x,
                    const float* __restrict__ Q, const float* __restrict__ R,
                    const float* __restrict__ Wi, const float* __restrict__ bi,
                    const float* __restrict__ Wg, const float* __restrict__ bg,
                    const float* __restrict__ Wste, const float* __restrict__ bste,
                    const float* __restrict__ Wfre, const float* __restrict__ bfre,
                    const float* __restrict__ Wom, const float* __restrict__ bom,
                    const float* __restrict__ Wo, const float* __restrict__ bo,
                    const float* __restrict__ Wa, const float* __restrict__ ba,
                    const float* __restrict__ Wout, const float* __restrict__ bout,
                    float* __restrict__ out)
{
    const int t = threadIdx.x;
    const int blk = blockIdx.x;

    __shared__ float sQ[HDIM * CDIM];                  // Q[k][c]
    __shared__ float sR[CDIM * HDIM];                  // R[k][j]
    // soh[320][4]: rows 0..63 = xt, 64..191 = h, 192..319 = c_t  ([dim][seq])
    __shared__ __align__(16) float soh[320][4];
    __shared__ __align__(16) float sit[HDIM][4];
    __shared__ __align__(16) float schat[HDIM][4];
    __shared__ __align__(16) float sfste[HDIM][4];
    __shared__ __align__(16) float sffre[FDIM][4];
    __shared__ __align__(16) float scosv[FDIM][4];
    __shared__ __align__(16) float ssinv[FDIM][4];
    __shared__ __align__(16) float spart[4096];        // 16 KB partials
    __shared__ float swa[FDIM];

    #pragma unroll
    for (int i = 0; i < 8; ++i) sQ[t + 1024 * i] = Q[t + 1024 * i];
    #pragma unroll
    for (int i = 0; i < 8; ++i) sR[t + 1024 * i] = R[t + 1024 * i];
    if (t < FDIM) swa[t] = Wa[t];
    if (t < 512) soh[64 + (t >> 2)][t & 3] = 0.0f;     // h = 0

    // per-thread complex state: (row, seq, f-half)
    const int srow = t >> 3, sseq = (t >> 1) & 3, shalf = t & 1;
    const int f0 = shalf * (FDIM / 2);
    float re[FDIM / 2], im[FDIM / 2];
    #pragma unroll
    for (int j = 0; j < FDIM / 2; ++j) { re[j] = 0.0f; im[j] = 0.0f; }

    // gate role: col = t>>1 (0..447), ks = t&1 (k-half). Shfl-pair reduce.
    const int gcol448 = t >> 1, gks = t & 1;
    const float* wG = nullptr; const float* bG = nullptr;
    int strG = HDIM, gcol = 0, reg = -1;
    if      (gcol448 < 128) { wG = Wi;   bG = bi;   strG = HDIM; gcol = gcol448;       reg = 0; }
    else if (gcol448 < 256) { wG = Wg;   bG = bg;   strG = HDIM; gcol = gcol448 - 128; reg = 1; }
    else if (gcol448 < 384) { wG = Wste; bG = bste; strG = HDIM; gcol = gcol448 - 256; reg = 2; }
    else if (gcol448 < 416) { wG = Wfre; bG = bfre; strG = FDIM; gcol = gcol448 - 384; reg = 3; }
    else if (gcol448 < 448) { wG = Wom;  bG = bom;  strG = FDIM; gcol = gcol448 - 416; reg = 4; }
    const float gb = (reg >= 0) ? bG[gcol] : 0.0f;
    const float* wGp0 = (reg >= 0) ? (wG + gcol + gks * 96 * strG) : Wi;

    const float ba0 = ba[0];
    const float bo_r = bo[t >> 2];                     // for out-reduce (t<512)
    const float* xbase = x + (size_t)blk * 4 * LSEQ * CDIM;

    const int ocol = t & 127, oks = t >> 7;            // out matvec: 128 cols x 8 k-slices
    const float* woP = Wo + ocol;

    // prologue: load x(ts=0)
    if (t < 256) soh[t & 63][t >> 6] = xbase[((t >> 6) * LSEQ) * CDIM + (t & 63)];
    __syncthreads();

    for (int ts = 0; ts < LSEQ; ++ts) {
        // ---- mogrify x,h,x,h,x ----
        #pragma unroll
        for (int m = 0; m < 5; ++m) {
            if ((m & 1) == 0) {
                // xt = 2*sig(h @ Q) * xt : 64 cols x 16 k-slices of 8
                const int c = t & 63, k0 = (t >> 6) * 8;
                float a0 = 0.f, a1 = 0.f, a2 = 0.f, a3 = 0.f;
                #pragma unroll
                for (int kk = 0; kk < 8; ++kk) {
                    const int k = k0 + kk;
                    const float qv = sQ[k * CDIM + c];
                    const float4 h4 = *(const float4*)&soh[64 + k][0];
                    a0 += qv * h4.x; a1 += qv * h4.y; a2 += qv * h4.z; a3 += qv * h4.w;
                }
                *(float4*)&spart[(t >> 6) * 256 + c * 4] = make_float4(a0, a1, a2, a3);
                __syncthreads();
                if (t < 256) {
                    float v = 0.f;
                    #pragma unroll
                    for (int i = 0; i < 16; ++i) v += spart[i * 256 + t];
                    soh[t >> 2][t & 3] = 2.0f * sigf(v) * soh[t >> 2][t & 3];
                }
                __syncthreads();
            } else {
                // h = 2*sig(x @ R) * h : 128 cols x 8 k-slices of 8
                const int j = t & 127, k0 = (t >> 7) * 8;
                float a0 = 0.f, a1 = 0.f, a2 = 0.f, a3 = 0.f;
                #pragma unroll
                for (int kk = 0; kk < 8; ++kk) {
                    const int k = k0 + kk;
                    const float rv = sR[k * HDIM + j];
                    const float4 x4 = *(const float4*)&soh[k][0];
                    a0 += rv * x4.x; a1 += rv * x4.y; a2 += rv * x4.z; a3 += rv * x4.w;
                }
                *(float4*)&spart[(t >> 7) * 512 + j * 4] = make_float4(a0, a1, a2, a3);
                __syncthreads();
                if (t < 512) {
                    float v = 0.f;
                    #pragma unroll
                    for (int i = 0; i < 8; ++i) v += spart[i * 512 + t];
                    soh[64 + (t >> 2)][t & 3] = 2.0f * sigf(v) * soh[64 + (t >> 2)][t & 3];
                }
                __syncthreads();
            }
        }

        // ---- gates: ih(192) @ [Wi|Wg|Wste|Wfre|Wom]; (col, k-half) on lane pairs ----
        if (gcol448 < 448) {
            float g0 = 0.f, g1 = 0.f, g2 = 0.f, g3 = 0.f;
            const float* wp = wGp0;
            const int kbase = gks * 96;
            #pragma unroll 8
            for (int kk = 0; kk < 96; ++kk) {
                const float w = *wp; wp += strG;
                const float4 i4 = *(const float4*)&soh[kbase + kk][0];
                g0 += w * i4.x; g1 += w * i4.y; g2 += w * i4.z; g3 += w * i4.w;
            }
            g0 += __shfl_xor(g0, 1); g1 += __shfl_xor(g1, 1);
            g2 += __shfl_xor(g2, 1); g3 += __shfl_xor(g3, 1);
            if (gks == 0) {
                g0 += gb; g1 += gb; g2 += gb; g3 += gb;
                if (reg == 4) {
                    const float o0 = TWO_PI * sigf(g0), o1 = TWO_PI * sigf(g1);
                    const float o2 = TWO_PI * sigf(g2), o3 = TWO_PI * sigf(g3);
                    *(float4*)&scosv[gcol][0] = make_float4(__cosf(o0), __cosf(o1), __cosf(o2), __cosf(o3));
                    *(float4*)&ssinv[gcol][0] = make_float4(__sinf(o0), __sinf(o1), __sinf(o2), __sinf(o3));
                } else {
                    float* d = (reg == 0) ? &sit[0][0] : (reg == 1) ? &schat[0][0]
                             : (reg == 2) ? &sfste[0][0] : &sffre[0][0];
                    *(float4*)&d[gcol * 4] = make_float4(sigf(g0), sigf(g1), sigf(g2), sigf(g3));
                }
            }
        }
        __syncthreads();

        // ---- complex state update + amplitude @ Wa -> c_t : (row,seq,f-half)/thread ----
        {
            const float ic = sit[srow][sseq] * schat[srow][sseq];
            const float fs = sfste[srow][sseq];
            float acc = 0.f;
            #pragma unroll
            for (int j = 0; j < FDIM / 2; ++j) {
                const int f = f0 + j;
                const float ft = fs * sffre[f][sseq];
                const float cv = scosv[f][sseq], sv = ssinv[f][sseq];
                re[j] = ft * re[j] + ic * cv;
                im[j] = ft * im[j] + ic * sv;
                acc += sqrtf(re[j] * re[j] + im[j] * im[j]) * swa[f];
            }
            acc += __shfl_xor(acc, 1);
            if (shalf == 0) soh[192 + srow][sseq] = tanh_fast(acc + ba0);
        }
        __syncthreads();

        // ---- o_t partial: oh(320) @ Wo, 128 cols x 8 k-slices of 40 ----
        {
            float o0 = 0.f, o1 = 0.f, o2 = 0.f, o3 = 0.f;
            const int k0 = oks * 40;
            #pragma unroll 8
            for (int kk = 0; kk < 40; ++kk) {
                const int k = k0 + kk;
                const float w = woP[k * HDIM];
                const float4 i4 = *(const float4*)&soh[k][0];
                o0 += w * i4.x; o1 += w * i4.y; o2 += w * i4.z; o3 += w * i4.w;
            }
            *(float4*)&spart[oks * 512 + ocol * 4] = make_float4(o0, o1, o2, o3);
        }
        __syncthreads();

        // ---- out reduce -> h update; overlap: load x(ts+1) ----
        if (t < 512) {
            float v = 0.f;
            #pragma unroll
            for (int i = 0; i < 8; ++i) v += spart[i * 512 + t];
            const float o = sigf(v + bo_r);
            soh[64 + (t >> 2)][t & 3] = o * tanh_fast(soh[192 + (t >> 2)][t & 3]);
        } else if (t < 768 && ts + 1 < LSEQ) {
            const int l = t - 512, c = l & 63, s2 = l >> 6;
            soh[c][s2] = xbase[(s2 * LSEQ + ts + 1) * CDIM + c];
        }
        __syncthreads();
    }

    // ---- out = h_last @ Wout + bout, one wave per sequence ----
    if (t < 256) {
        const int w = t >> 6, l = t & 63;
        float p = soh[64 + l][w] * Wout[l] + soh[128 + l][w] * Wout[64 + l];
        #pragma unroll
        for (int off = 32; off > 0; off >>= 1) p += __shfl_xor(p, off);
        if (l == 0) out[blk * 4 + w] = p + bout[0];
    }
}

extern "C" void kernel_launch(void* const* d_in, const int* in_sizes, int n_in,
                              void* d_out, int out_size, void* d_ws, size_t ws_size,
                              hipStream_t stream) {
    const float* x    = (const float*)d_in[0];
    const float* Q    = (const float*)d_in[1];
    const float* R    = (const float*)d_in[2];
    const float* Wi   = (const float*)d_in[3];
    const float* bi   = (const float*)d_in[4];
    const float* Wg   = (const float*)d_in[5];
    const float* bg   = (const float*)d_in[6];
    const float* Wste = (const float*)d_in[7];
    const float* bste = (const float*)d_in[8];
    const float* Wfre = (const float*)d_in[9];
    const float* bfre = (const float*)d_in[10];
    const float* Wom  = (const float*)d_in[11];
    const float* bom  = (const float*)d_in[12];
    const float* Wo   = (const float*)d_in[13];
    const float* bo   = (const float*)d_in[14];
    const float* Wa   = (const float*)d_in[15];
    const float* ba   = (const float*)d_in[16];
    const float* Wout = (const float*)d_in[17];
    const float* bout = (const float*)d_in[18];
    float* out = (float*)d_out;

    sfm_lstm_s4w16<<<dim3(256), dim3(1024), 0, stream>>>(
        x, Q, R, Wi, bi, Wg, bg, Wste, bste, Wfre, bfre, Wom, bom,
        Wo, bo, Wa, ba, Wout, bout, out);
}